// Round 5
// baseline (2414.107 us; speedup 1.0000x reference)
//
#include <hip/hip_runtime.h>
#include <cstdint>
#include <cstddef>

#define EMBED  256
#define HIDDEN 512
#define VOCAB  32000
#define BATCH  16
#define TCAP   63
#define STEPS  1024   // BATCH * (TCAP + 1)
#define GROWS  2048   // 4 * HIDDEN gate rows
#define NCONV  224    // converter WGs = 256 - 32 scan WGs

// ws layout (bytes)
#define WS_FAST  0                         // u64[2][512] fast (same-XCD L2) 8 KB
#define WS_SLOW  8192                      // u64[2][512] slow (MALL/agent)  8 KB
#define WS_CTRS  16384                     // u32 counters (claim/done/ticket)
#define WS_HS32  16640                     // float[1024][512]  2 MB
#define WS_HSBF  (16640 + 2097152)         // bf16 [1024][512]  1 MB
#define WS_WB    (16640 + 3145728)         // bf16 [32000][512] 31.25 MB region
#define WS_XPOFF (24u * 1024u * 1024u)     // xp overlays Wb tail 8 MB
#define WS_NEED  (3162368ull + 33554432ull)
#define WB_HEAD_ELEMS 12582912             // Wb elems below the xp overlay

typedef __bf16 bf16x8 __attribute__((ext_vector_type(8)));
typedef float  f32x4  __attribute__((ext_vector_type(4)));
typedef unsigned int u32x4v __attribute__((ext_vector_type(4)));

// ---------------------------------------------------------------------------
// helpers
// ---------------------------------------------------------------------------
__device__ __forceinline__ float sigmoid_f(float x) {
    return 1.0f / (1.0f + __expf(-x));
}
__device__ __forceinline__ float tanh_f(float x) {
    float a = fabsf(x);
    float e = __expf(-2.0f * a);
    float r = (1.0f - e) / (1.0f + e);
    return copysignf(r, x);
}
__device__ __forceinline__ float sel4(float a0, float a1, float a2, float a3, int j) {
    float lo = (j & 1) ? a1 : a0;
    float hi = (j & 1) ? a3 : a2;
    return (j & 2) ? hi : lo;
}
__device__ __forceinline__ unsigned short f2bf_u16(float f) {
    union { float f; unsigned u; } v; v.f = f;
    unsigned r = v.u + 0x7fffu + ((v.u >> 16) & 1u);
    return (unsigned short)(r >> 16);
}

// ---------------------------------------------------------------------------
// Kernel 0: xp[s][r] = xs[s] . W_ih[r] + b_ih[r] + b_hh[r]
// ---------------------------------------------------------------------------
__global__ __launch_bounds__(256) void xproj_kernel(
    const float* __restrict__ features,
    const int*   __restrict__ captions,
    const float* __restrict__ emb,
    const float* __restrict__ W_ih,
    const float* __restrict__ b_ih,
    const float* __restrict__ b_hh,
    float* __restrict__ xp)            // [STEPS][GROWS]
{
    __shared__ float As[64][65];
    __shared__ float Bs[64][65];
    const int tid = threadIdx.x;
    const int tx = tid & 15, ty = tid >> 4;
    const int r0 = blockIdx.x * 64;
    const int s0 = blockIdx.y * 64;
    float accv[4][4] = {};

    for (int k0 = 0; k0 < EMBED; k0 += 64) {
#pragma unroll
        for (int i = 0; i < 4; ++i) {
            const int idx = tid + i * 256;
            const int row = idx >> 4, q = idx & 15;
            const int s = s0 + row, sb = s >> 6, st = s & 63;
            const float* xr = (st == 0)
                ? (features + (size_t)sb * EMBED)
                : (emb + (size_t)captions[sb * TCAP + st - 1] * EMBED);
            const float4 a = *(const float4*)(xr + k0 + q * 4);
            As[row][q * 4 + 0] = a.x; As[row][q * 4 + 1] = a.y;
            As[row][q * 4 + 2] = a.z; As[row][q * 4 + 3] = a.w;
            const float4 b = *(const float4*)(W_ih + (size_t)(r0 + row) * EMBED + k0 + q * 4);
            Bs[row][q * 4 + 0] = b.x; Bs[row][q * 4 + 1] = b.y;
            Bs[row][q * 4 + 2] = b.z; Bs[row][q * 4 + 3] = b.w;
        }
        __syncthreads();
#pragma unroll 16
        for (int kk = 0; kk < 64; ++kk) {
            float av[4], bv[4];
#pragma unroll
            for (int i = 0; i < 4; ++i) av[i] = As[ty * 4 + i][kk];
#pragma unroll
            for (int j = 0; j < 4; ++j) bv[j] = Bs[tx * 4 + j][kk];
#pragma unroll
            for (int i = 0; i < 4; ++i)
#pragma unroll
                for (int j = 0; j < 4; ++j)
                    accv[i][j] = fmaf(av[i], bv[j], accv[i][j]);
        }
        __syncthreads();
    }
#pragma unroll
    for (int j = 0; j < 4; ++j) {
        const int r = r0 + tx * 4 + j;
        const float bb = b_ih[r] + b_hh[r];
#pragma unroll
        for (int i = 0; i < 4; ++i)
            xp[(size_t)(s0 + ty * 4 + i) * GROWS + r] = accv[i][j] + bb;
    }
}

// ---------------------------------------------------------------------------
// Kernel 1: persistent sequential LSTM scan, XCD-pinned fast transport.
// 256 WGs launched. Each reads HW_REG_XCC_ID; WGs on XCD 0 claim the 32
// scan slots (atomic ticket; timeout fallback lets any WG fill leftover
// slots -> deadlock-free). Losers run the W_out fp32->bf16 head conversion.
// A packed counter (low16=claims, high16=off-target claims) tells every
// slot holder whether all 32 landed on one XCD.
//
// Transport (uniform): producer -> volatile u64 store (vL1 write-through ->
// shared XCD L2); consumer -> inline-asm global_load_dwordx4 sc0 (L1 bypass,
// L2 served).  ~200cy hop instead of ~800cy MALL.
// Transport (mixed / model-failure): agent-scope atomics on a second buffer
// (round-4 protocol).  Producers ALWAYS double-publish to both buffers; a
// wave whose fast poll spins 2048 rounds sticky-flips to slow. No hang mode.
// Slot-reuse safety: parity double-buffer + tag-in-word (see round 3/4).
// ---------------------------------------------------------------------------
__global__ __launch_bounds__(256, 1) void lstm_scan_kernel(
    const float* __restrict__ W_hh,
    const float* __restrict__ xp,              // [STEPS][GROWS]
    unsigned long long* __restrict__ fastb,    // [2][HIDDEN]
    unsigned long long* __restrict__ slowb,    // [2][HIDDEN]
    unsigned* __restrict__ ctrs,               // [0]=slot_claim [1]=claims_done [2]=conv_ticket
    float* __restrict__ hs32,                  // [STEPS][HIDDEN]
    __bf16* __restrict__ hsbf,                 // [STEPS][HIDDEN]
    const float* __restrict__ W_out,
    unsigned short* __restrict__ Wb,
    const int wbf)
{
    const int tid = threadIdx.x;
    __shared__ int sh_slot, sh_uni, sh_ticket;

    // ---- claim phase (tid 0 only, broadcast via LDS) ----
    if (tid == 0) {
        unsigned xcd;
        asm volatile("s_getreg_b32 %0, hwreg(HW_REG_XCC_ID)" : "=s"(xcd));
        int id = -1;
        if (xcd == 0u) {
            const unsigned c = __hip_atomic_fetch_add(ctrs + 0, 1u,
                __ATOMIC_RELAXED, __HIP_MEMORY_SCOPE_AGENT);
            if (c < 32u) id = (int)c;
        }
        if (id < 0) {
            // wait for target-XCD WGs to fill the slots; timeout -> self-claim
            for (int t = 0; t < 24; ++t) {
                if (__hip_atomic_load(ctrs + 0, __ATOMIC_RELAXED,
                                      __HIP_MEMORY_SCOPE_AGENT) >= 32u) break;
                __builtin_amdgcn_s_sleep(127);
            }
            if (__hip_atomic_load(ctrs + 0, __ATOMIC_RELAXED,
                                  __HIP_MEMORY_SCOPE_AGENT) < 32u) {
                const unsigned c = __hip_atomic_fetch_add(ctrs + 0, 1u,
                    __ATOMIC_RELAXED, __HIP_MEMORY_SCOPE_AGENT);
                if (c < 32u) id = (int)c;
            }
        }
        int uni = 0;
        if (id >= 0) {
            __hip_atomic_fetch_add(ctrs + 1, 1u | ((xcd == 0u) ? 0u : 0x10000u),
                                   __ATOMIC_RELAXED, __HIP_MEMORY_SCOPE_AGENT);
            unsigned cd;
            for (;;) {
                cd = __hip_atomic_load(ctrs + 1, __ATOMIC_RELAXED,
                                       __HIP_MEMORY_SCOPE_AGENT);
                if ((cd & 0xffffu) >= 32u) break;
                __builtin_amdgcn_s_sleep(2);
            }
            uni = ((cd >> 16) == 0u) ? 1 : 0;
        } else {
            sh_ticket = (int)__hip_atomic_fetch_add(ctrs + 2, 1u,
                __ATOMIC_RELAXED, __HIP_MEMORY_SCOPE_AGENT);
        }
        sh_slot = id;
        sh_uni = uni;
    }
    __syncthreads();
    const int slot = sh_slot;

    if (slot < 0) {
        // ---- converter: W_out fp32 -> bf16 head region ----
        if (!wbf) return;
        const int ticket = sh_ticket;
        const int stride = NCONV * 256 * 4;
        for (int i = (ticket * 256 + tid) * 4; i < WB_HEAD_ELEMS; i += stride) {
            const float4 v = *(const float4*)(W_out + i);
            ushort4 o;
            o.x = f2bf_u16(v.x); o.y = f2bf_u16(v.y);
            o.z = f2bf_u16(v.z); o.w = f2bf_u16(v.w);
            *(ushort4*)(Wb + i) = o;
        }
        return;
    }

    bool usefast = (sh_uni != 0);

    const int rg  = tid >> 6;
    const int kc  = tid & 63;
    const int w   = slot * 4 + rg;         // global wave 0..127
    const int j0  = w * 4;

    __shared__ float hlds[2][HIDDEN];      // double-buffered h broadcast

    const int t_own  = ((kc & 1) << 1) | ((kc >> 1) & 1);
    const int jj_own = (((kc >> 2) & 1) << 1) | ((kc >> 3) & 1);
    const int row_own = t_own * HIDDEN + j0 + jj_own;

    // ---- W_hh slice into registers: 16 rows x 8 k-chunk per lane ----
    float Whh[4][4][8];
#pragma unroll
    for (int t = 0; t < 4; ++t) {
#pragma unroll
        for (int jj = 0; jj < 4; ++jj) {
            const int row = t * HIDDEN + j0 + jj;
            const float4* ph = (const float4*)(W_hh + (size_t)row * HIDDEN + kc * 8);
            const float4 h0 = ph[0], h1 = ph[1];
            Whh[t][jj][0] = h0.x; Whh[t][jj][1] = h0.y; Whh[t][jj][2] = h0.z; Whh[t][jj][3] = h0.w;
            Whh[t][jj][4] = h1.x; Whh[t][jj][5] = h1.y; Whh[t][jj][6] = h1.z; Whh[t][jj][7] = h1.w;
        }
    }

    float c_state = 0.0f;
    float xpv_next = xp[row_own];          // xp for s = 0
    const int qi = rg * 128 + kc * 2;      // my quarter words

    for (int s = 0; s < STEPS; ++s) {
        const int p = s & 1;
        const unsigned expect = (unsigned)s;
        const float xpv = xpv_next;

        // prefetch next step's xp (independent of h)
        const int sn = (s + 1 < STEPS) ? (s + 1) : (STEPS - 1);
        xpv_next = xp[(size_t)sn * GROWS + row_own];

        // ---- poll my quarter of version s ----
        unsigned d0, d1;
        const unsigned long long fa = (unsigned long long)(fastb + (size_t)p * HIDDEN + qi);
        if (usefast) {
            int it = 0;
            for (;;) {
                u32x4v v;
                asm volatile("global_load_dwordx4 %0, %1, off sc0\n\t"
                             "s_waitcnt vmcnt(0)"
                             : "=v"(v) : "v"(fa) : "memory");
                const bool ok = (v.y == expect) & (v.w == expect);
                if (__all((int)ok)) { d0 = v.x; d1 = v.z; break; }
                if (++it >= 2048) { usefast = false; break; }  // sticky fallback
            }
        }
        if (!usefast) {
            const unsigned long long* hb = slowb + (size_t)p * HIDDEN + qi;
            unsigned long long va, vb;
            for (;;) {
                va = __hip_atomic_load(hb,     __ATOMIC_RELAXED, __HIP_MEMORY_SCOPE_AGENT);
                vb = __hip_atomic_load(hb + 1, __ATOMIC_RELAXED, __HIP_MEMORY_SCOPE_AGENT);
                const bool ok = ((unsigned)(va >> 32) == expect) &
                                ((unsigned)(vb >> 32) == expect);
                if (__all((int)ok)) break;
                __builtin_amdgcn_s_sleep(1);
            }
            d0 = (unsigned)(va & 0xffffffffULL);
            d1 = (unsigned)(vb & 0xffffffffULL);
        }
        hlds[p][qi]     = __uint_as_float(d0);
        hlds[p][qi + 1] = __uint_as_float(d1);
        __syncthreads();

        // ---- h from LDS ----
        float hreg[8];
        {
            const float4 a = *(const float4*)&hlds[p][kc * 8];
            const float4 b = *(const float4*)&hlds[p][kc * 8 + 4];
            hreg[0] = a.x; hreg[1] = a.y; hreg[2] = a.z; hreg[3] = a.w;
            hreg[4] = b.x; hreg[5] = b.y; hreg[6] = b.z; hreg[7] = b.w;
        }

        // ---- h contribution: 16 rows x 8 k ----
        float acc[16];
#pragma unroll
        for (int t = 0; t < 4; ++t) {
#pragma unroll
            for (int jj = 0; jj < 4; ++jj) {
                float a = Whh[t][jj][0] * hreg[0];
#pragma unroll
                for (int kk = 1; kk < 8; ++kk)
                    a = fmaf(Whh[t][jj][kk], hreg[kk], a);
                acc[t * 4 + jj] = a;
            }
        }

        // ---- fold-reduce 16 x 64 lanes -> full sum per lane ----
#pragma unroll
        for (int i = 0; i < 8; ++i) {
            const float send = (kc & 1) ? acc[i] : acc[i + 8];
            const float keep = (kc & 1) ? acc[i + 8] : acc[i];
            acc[i] = keep + __shfl_xor(send, 1, 64);
        }
#pragma unroll
        for (int i = 0; i < 4; ++i) {
            const float send = (kc & 2) ? acc[i] : acc[i + 4];
            const float keep = (kc & 2) ? acc[i + 4] : acc[i];
            acc[i] = keep + __shfl_xor(send, 2, 64);
        }
#pragma unroll
        for (int i = 0; i < 2; ++i) {
            const float send = (kc & 4) ? acc[i] : acc[i + 2];
            const float keep = (kc & 4) ? acc[i + 2] : acc[i];
            acc[i] = keep + __shfl_xor(send, 4, 64);
        }
        {
            const float send = (kc & 8) ? acc[0] : acc[1];
            const float keep = (kc & 8) ? acc[1] : acc[0];
            acc[0] = keep + __shfl_xor(send, 8, 64);
        }
        float a = acc[0];
        a += __shfl_xor(a, 16, 64);
        a += __shfl_xor(a, 32, 64);
        a += xpv;   // full gate pre-activation for (t_own, jj_own)

        // ---- gather the 4 gates of MY element ----
        const float g00 = a;
        const float g01 = __shfl_xor(a, 1, 64);
        const float g10 = __shfl_xor(a, 2, 64);
        const float g11 = __shfl_xor(g01, 2, 64);
        float gi = sel4(g00, g10, g01, g11, t_own);
        float gf = sel4(g00, g10, g01, g11, t_own ^ 1);
        float gg = sel4(g00, g10, g01, g11, t_own ^ 2);
        float go = sel4(g00, g10, g01, g11, t_own ^ 3);

        gi = sigmoid_f(gi);
        gf = sigmoid_f(gf);
        gg = tanh_f(gg);
        go = sigmoid_f(go);
        c_state = gf * c_state + gi * gg;
        const float hnew = go * tanh_f(c_state);

        // ---- publish version s+1: fast (L2) + slow (MALL), then trace ----
        const int q = (s + 1) & 1;
        if ((kc & 0x33) == 0) {
            const int j = j0 + jj_own;
            const unsigned long long pack =
                ((unsigned long long)(unsigned)(s + 1) << 32) |
                (unsigned long long)__float_as_uint(hnew);
            *(volatile unsigned long long*)(fastb + (size_t)q * HIDDEN + j) = pack;
            __hip_atomic_store(slowb + (size_t)q * HIDDEN + j, pack,
                               __ATOMIC_RELAXED, __HIP_MEMORY_SCOPE_AGENT);
            if (wbf) hsbf[(size_t)s * HIDDEN + j] = (__bf16)hnew;
            else     hs32[(size_t)s * HIDDEN + j] = hnew;
        }
    }
}

// ---------------------------------------------------------------------------
// Kernel 1b: convert the xp-protected tail of W_out after the scan.
// ---------------------------------------------------------------------------
__global__ __launch_bounds__(256) void convert_tail_kernel(
    const float* __restrict__ W, unsigned short* __restrict__ Wb,
    int lo, int n)
{
    const int stride = gridDim.x * blockDim.x * 4;
    for (int i = lo + (blockIdx.x * blockDim.x + threadIdx.x) * 4; i < n; i += stride) {
        const float4 v = *(const float4*)(W + i);
        ushort4 o;
        o.x = f2bf_u16(v.x); o.y = f2bf_u16(v.y);
        o.z = f2bf_u16(v.z); o.w = f2bf_u16(v.w);
        *(ushort4*)(Wb + i) = o;
    }
}

// ---------------------------------------------------------------------------
// Kernel 2b: logits = hs_bf16 @ Wb^T + b_out via MFMA (M=1024,N=32000,K=512).
// ---------------------------------------------------------------------------
__global__ __launch_bounds__(256) void logits_mfma_kernel(
    const __bf16* __restrict__ A,
    const __bf16* __restrict__ B,
    const float* __restrict__ b_out,
    float* __restrict__ out)
{
    __shared__ char AsR[16384];
    __shared__ char BsR[16384];
    const int tid  = threadIdx.x;
    const int lane = tid & 63;
    const int wave = tid >> 6;
    const int wm = (wave >> 1) * 64;
    const int wn = (wave & 1) * 64;
    const int n0 = blockIdx.x * 128;
    const int m0 = blockIdx.y * 128;

    f32x4 acc[4][4] = {};

    for (int k0 = 0; k0 < HIDDEN; k0 += 64) {
        if (k0) __syncthreads();
#pragma unroll
        for (int i = 0; i < 4; ++i) {
            const int o   = (tid + i * 256) << 4;
            const int row = o >> 7;
            const int cb  = o & 127;
            const int sc  = cb ^ ((row & 7) << 4);
            const bf16x8 av = *(const bf16x8*)(A + (size_t)(m0 + row) * HIDDEN + k0 + (cb >> 1));
            const bf16x8 bv = *(const bf16x8*)(B + (size_t)(n0 + row) * HIDDEN + k0 + (cb >> 1));
            *(bf16x8*)(AsR + row * 128 + sc) = av;
            *(bf16x8*)(BsR + row * 128 + sc) = bv;
        }
        __syncthreads();
#pragma unroll
        for (int ks = 0; ks < 2; ++ks) {
            const int kb = ks * 64 + ((lane >> 4) << 4);
            bf16x8 af[4], bfr[4];
#pragma unroll
            for (int mi = 0; mi < 4; ++mi) {
                const int r = wm + mi * 16 + (lane & 15);
                af[mi] = *(const bf16x8*)(AsR + r * 128 + (kb ^ ((r & 7) << 4)));
            }
#pragma unroll
            for (int ni = 0; ni < 4; ++ni) {
                const int r = wn + ni * 16 + (lane & 15);
                bfr[ni] = *(const bf16x8*)(BsR + r * 128 + (kb ^ ((r & 7) << 4)));
            }
#pragma unroll
            for (int mi = 0; mi < 4; ++mi)
#pragma unroll
                for (int ni = 0; ni < 4; ++ni)
                    acc[mi][ni] = __builtin_amdgcn_mfma_f32_16x16x32_bf16(
                        af[mi], bfr[ni], acc[mi][ni], 0, 0, 0);
        }
    }

#pragma unroll
    for (int ni = 0; ni < 4; ++ni) {
        const int col = n0 + wn + ni * 16 + (lane & 15);
        const float bo = b_out[col];
#pragma unroll
        for (int mi = 0; mi < 4; ++mi) {
            const int r0 = m0 + wm + mi * 16 + ((lane >> 4) << 2);
#pragma unroll
            for (int qq = 0; qq < 4; ++qq)
                out[(size_t)(r0 + qq) * VOCAB + col] = acc[mi][ni][qq] + bo;
        }
    }
}

// ---------------------------------------------------------------------------
// Kernel 2-fallback: fp32 vector GEMM.
// ---------------------------------------------------------------------------
__global__ __launch_bounds__(256) void logits_kernel(
    const float* __restrict__ hs,
    const float* __restrict__ W_out,
    const float* __restrict__ b_out,
    float* __restrict__ out)
{
    __shared__ float As[64][65];
    __shared__ float Bs[64][65];
    const int tid = threadIdx.x;
    const int tx = tid & 15, ty = tid >> 4;
    const int v0 = blockIdx.x * 64;
    const int s0 = blockIdx.y * 64;
    float accv[4][4] = {};

    for (int k0 = 0; k0 < HIDDEN; k0 += 64) {
#pragma unroll
        for (int i = 0; i < 4; ++i) {
            const int idx = tid + i * 256;
            const int r = idx >> 4, q = idx & 15;
            const float4 a = *(const float4*)(hs + (size_t)(s0 + r) * HIDDEN + k0 + q * 4);
            As[r][q * 4 + 0] = a.x; As[r][q * 4 + 1] = a.y;
            As[r][q * 4 + 2] = a.z; As[r][q * 4 + 3] = a.w;
            const float4 b = *(const float4*)(W_out + (size_t)(v0 + r) * HIDDEN + k0 + q * 4);
            Bs[r][q * 4 + 0] = b.x; Bs[r][q * 4 + 1] = b.y;
            Bs[r][q * 4 + 2] = b.z; Bs[r][q * 4 + 3] = b.w;
        }
        __syncthreads();
#pragma unroll 16
        for (int kk = 0; kk < 64; ++kk) {
            float av[4], bv[4];
#pragma unroll
            for (int i = 0; i < 4; ++i) av[i] = As[ty * 4 + i][kk];
#pragma unroll
            for (int j = 0; j < 4; ++j) bv[j] = Bs[tx * 4 + j][kk];
#pragma unroll
            for (int i = 0; i < 4; ++i)
#pragma unroll
                for (int j = 0; j < 4; ++j)
                    accv[i][j] = fmaf(av[i], bv[j], accv[i][j]);
        }
        __syncthreads();
    }
#pragma unroll
    for (int i = 0; i < 4; ++i) {
        const int s = s0 + ty * 4 + i;
#pragma unroll
        for (int j = 0; j < 4; ++j) {
            const int v = v0 + tx * 4 + j;
            out[(size_t)s * VOCAB + v] = accv[i][j] + b_out[v];
        }
    }
}

// ---------------------------------------------------------------------------
// Kernel 3: in-place row softmax, one WG per row of 32000.
// ---------------------------------------------------------------------------
__global__ __launch_bounds__(256) void softmax_kernel(float* __restrict__ out)
{
    const int row = blockIdx.x;
    float* p = out + (size_t)row * VOCAB;
    const int tid = threadIdx.x;
    __shared__ float redm[4];
    __shared__ float reds[4];

    float m = -3.402823466e38f;
    for (int idx = tid * 4; idx < VOCAB; idx += 1024) {
        const float4 v = *(const float4*)(p + idx);
        m = fmaxf(m, fmaxf(fmaxf(v.x, v.y), fmaxf(v.z, v.w)));
    }
#pragma unroll
    for (int d = 1; d < 64; d <<= 1) m = fmaxf(m, __shfl_xor(m, d, 64));
    if ((tid & 63) == 0) redm[tid >> 6] = m;
    __syncthreads();
    m = fmaxf(fmaxf(redm[0], redm[1]), fmaxf(redm[2], redm[3]));

    float sum = 0.f;
    for (int idx = tid * 4; idx < VOCAB; idx += 1024) {
        const float4 v = *(const float4*)(p + idx);
        sum += __expf(v.x - m) + __expf(v.y - m) + __expf(v.z - m) + __expf(v.w - m);
    }
#pragma unroll
    for (int d = 1; d < 64; d <<= 1) sum += __shfl_xor(sum, d, 64);
    if ((tid & 63) == 0) reds[tid >> 6] = sum;
    __syncthreads();
    sum = reds[0] + reds[1] + reds[2] + reds[3];
    const float inv = 1.0f / sum;

    for (int idx = tid * 4; idx < VOCAB; idx += 1024) {
        const float4 v = *(const float4*)(p + idx);
        float4 o;
        o.x = __expf(v.x - m) * inv;
        o.y = __expf(v.y - m) * inv;
        o.z = __expf(v.z - m) * inv;
        o.w = __expf(v.w - m) * inv;
        *(float4*)(p + idx) = o;
    }
}

// ---------------------------------------------------------------------------
// launch
// ---------------------------------------------------------------------------
extern "C" void kernel_launch(void* const* d_in, const int* in_sizes, int n_in,
                              void* d_out, int out_size, void* d_ws, size_t ws_size,
                              hipStream_t stream)
{
    const float* features = (const float*)d_in[0];
    const int*   captions = (const int*)d_in[1];
    const float* emb      = (const float*)d_in[2];
    const float* W_ih     = (const float*)d_in[3];
    const float* W_hh     = (const float*)d_in[4];
    const float* b_ih     = (const float*)d_in[5];
    const float* b_hh     = (const float*)d_in[6];
    const float* W_out    = (const float*)d_in[7];
    const float* b_out    = (const float*)d_in[8];
    float* out = (float*)d_out;

    char* ws = (char*)d_ws;
    unsigned long long* fastb = (unsigned long long*)(ws + WS_FAST);
    unsigned long long* slowb = (unsigned long long*)(ws + WS_SLOW);
    unsigned*           ctrs  = (unsigned*)(ws + WS_CTRS);
    float*              hs32  = (float*)(ws + WS_HS32);
    __bf16*             hsbf  = (__bf16*)(ws + WS_HSBF);
    __bf16*             Wb    = (__bf16*)(ws + WS_WB);
    const bool mfma_ok = ws_size >= WS_NEED;
    float* xpb = mfma_ok ? (float*)(ws + WS_WB + WS_XPOFF) : (float*)(ws + WS_WB);

    // reset transport buffers + claim counters (graph-replay determinism)
    hipMemsetAsync(d_ws, 0, WS_HS32, stream);

    xproj_kernel<<<dim3(GROWS / 64, STEPS / 64), 256, 0, stream>>>(
        features, captions, emb, W_ih, b_ih, b_hh, xpb);

    lstm_scan_kernel<<<256, 256, 0, stream>>>(
        W_hh, xpb, fastb, slowb, ctrs, hs32, hsbf,
        W_out, (unsigned short*)Wb, mfma_ok ? 1 : 0);

    if (mfma_ok) {
        convert_tail_kernel<<<512, 256, 0, stream>>>(
            W_out, (unsigned short*)Wb, WB_HEAD_ELEMS, VOCAB * HIDDEN);
        logits_mfma_kernel<<<dim3(VOCAB / 128, STEPS / 128), 256, 0, stream>>>(
            hsbf, Wb, b_out, out);
    } else {
        logits_kernel<<<dim3(VOCAB / 64, STEPS / 64), 256, 0, stream>>>(
            hs32, W_out, b_out, out);
    }
    softmax_kernel<<<STEPS, 256, 0, stream>>>(out);
}

// Round 8
// 2349.175 us; speedup vs baseline: 1.0276x; 1.0276x over previous
//
#include <hip/hip_runtime.h>
#include <cstdint>
#include <cstddef>

#define EMBED  256
#define HIDDEN 512
#define VOCAB  32000
#define BATCH  16
#define TCAP   63
#define STEPS  1024   // BATCH * (T+1)
#define GROWS  2048   // 4 * HIDDEN gate rows

// ws layout (bytes)
#define WS_PBUF  0                      // u64[32][2][512] private mailboxes (256 KB)
#define WS_HSBF  262144                 // bf16 [1024][512]   (1 MB)
#define WS_HS32  1310720                // float[1024][512]   (2 MB, fallback)
#define WS_WB    3407872                // bf16 [32000][512]  (31.25 MB)
#define WS_XPOFF (24u * 1024u * 1024u)  // xp overlays Wb tail 8 MB
#define WS_NEED  36962304ull
#define WB_HEAD_ELEMS 12582912          // Wb elems below the xp overlay

typedef __bf16 bf16x8 __attribute__((ext_vector_type(8)));
typedef float  f32x4  __attribute__((ext_vector_type(4)));
typedef unsigned int u32x4v __attribute__((ext_vector_type(4)));

// ---------------------------------------------------------------------------
// helpers
// ---------------------------------------------------------------------------
__device__ __forceinline__ float sigmoid_f(float x) {
    return 1.0f / (1.0f + __expf(-x));
}
__device__ __forceinline__ float tanh_f(float x) {
    float a = fabsf(x);
    float e = __expf(-2.0f * a);
    float r = (1.0f - e) / (1.0f + e);
    return copysignf(r, x);
}
__device__ __forceinline__ float sel4(float a0, float a1, float a2, float a3, int j) {
    float lo = (j & 1) ? a1 : a0;
    float hi = (j & 1) ? a3 : a2;
    return (j & 2) ? hi : lo;
}
__device__ __forceinline__ int sel4i(int a0, int a1, int a2, int a3, int j) {
    int lo = (j & 1) ? a1 : a0;
    int hi = (j & 1) ? a3 : a2;
    return (j & 2) ? hi : lo;
}
__device__ __forceinline__ unsigned short f2bf_u16(float f) {
    union { float f; unsigned u; } v; v.f = f;
    unsigned r = v.u + 0x7fffu + ((v.u >> 16) & 1u);
    return (unsigned short)(r >> 16);
}

// ---------------------------------------------------------------------------
// Kernel 0 (fused): xp GEMM + W_out head fp32->bf16 conversion.
//   blocks (x, y<16):  xp[s][r] = xs[s].W_ih[r] + b_ih[r] + b_hh[r]
//   blocks (x, y>=16): convert W_out[0..WB_HEAD_ELEMS)
// ---------------------------------------------------------------------------
__global__ __launch_bounds__(256) void xproj_conv_kernel(
    const float* __restrict__ features,
    const int*   __restrict__ captions,
    const float* __restrict__ emb,
    const float* __restrict__ W_ih,
    const float* __restrict__ b_ih,
    const float* __restrict__ b_hh,
    float* __restrict__ xp,             // [STEPS][GROWS]
    const float* __restrict__ W_out,
    unsigned short* __restrict__ Wb,
    const int wbf)
{
    const int tid = threadIdx.x;

    if (blockIdx.y >= 16) {
        if (!wbf) return;
        const int cid = (blockIdx.y - 16) * 32 + blockIdx.x;   // 0..255
        const int stride = 256 * 256 * 4;
        for (int i = (cid * 256 + tid) * 4; i < WB_HEAD_ELEMS; i += stride) {
            const float4 v = *(const float4*)(W_out + i);
            ushort4 o;
            o.x = f2bf_u16(v.x); o.y = f2bf_u16(v.y);
            o.z = f2bf_u16(v.z); o.w = f2bf_u16(v.w);
            *(ushort4*)(Wb + i) = o;
        }
        return;
    }

    __shared__ float As[64][65];
    __shared__ float Bs[64][65];
    const int tx = tid & 15, ty = tid >> 4;
    const int r0 = blockIdx.x * 64;
    const int s0 = blockIdx.y * 64;
    float accv[4][4] = {};

    for (int k0 = 0; k0 < EMBED; k0 += 64) {
#pragma unroll
        for (int i = 0; i < 4; ++i) {
            const int idx = tid + i * 256;
            const int row = idx >> 4, q = idx & 15;
            const int s = s0 + row, sb = s >> 6, st = s & 63;
            const float* xr = (st == 0)
                ? (features + (size_t)sb * EMBED)
                : (emb + (size_t)captions[sb * TCAP + st - 1] * EMBED);
            const float4 a = *(const float4*)(xr + k0 + q * 4);
            As[row][q * 4 + 0] = a.x; As[row][q * 4 + 1] = a.y;
            As[row][q * 4 + 2] = a.z; As[row][q * 4 + 3] = a.w;
            const float4 b = *(const float4*)(W_ih + (size_t)(r0 + row) * EMBED + k0 + q * 4);
            Bs[row][q * 4 + 0] = b.x; Bs[row][q * 4 + 1] = b.y;
            Bs[row][q * 4 + 2] = b.z; Bs[row][q * 4 + 3] = b.w;
        }
        __syncthreads();
#pragma unroll 16
        for (int kk = 0; kk < 64; ++kk) {
            float av[4], bv[4];
#pragma unroll
            for (int i = 0; i < 4; ++i) av[i] = As[ty * 4 + i][kk];
#pragma unroll
            for (int j = 0; j < 4; ++j) bv[j] = Bs[tx * 4 + j][kk];
#pragma unroll
            for (int i = 0; i < 4; ++i)
#pragma unroll
                for (int j = 0; j < 4; ++j)
                    accv[i][j] = fmaf(av[i], bv[j], accv[i][j]);
        }
        __syncthreads();
    }
#pragma unroll
    for (int j = 0; j < 4; ++j) {
        const int r = r0 + tx * 4 + j;
        const float bb = b_ih[r] + b_hh[r];
#pragma unroll
        for (int i = 0; i < 4; ++i)
            xp[(size_t)(s0 + ty * 4 + i) * GROWS + r] = accv[i][j] + bb;
    }
}

// ---------------------------------------------------------------------------
// Kernel 1: persistent sequential LSTM scan, push-multicast mailboxes.
// 32 WGs x 4 waves; wave w owns h elements [4w,4w+4); W_hh in VGPRs.
//
// Transport: producers fan the tagged word (s+1)<<32|h_bits out to ALL 32
// WG-private copies pbuf[c][parity][512]. Consumer WG g polls ONLY copy g
// (4 waves quarter it, 2 u64 = 1 dwordx4/lane) -> ~1 reader wave per line,
// no reader/writer line contention at the coherence point.
//
// CORRECTNESS (round-6/7 lesson): the poll load and its s_waitcnt vmcnt(0)
// MUST live in ONE asm statement with an early-clobber output. Split
// issue/wait lets regalloc insert backedge copies / overlap the address
// pair with the destination quad while the load is in flight (rule-#18
// class) -> stale data under a fresh tag -> ~1e-5 drift. Fused asm has no
// window. The hlds exchange uses __syncthreads() (raw s_barrier is
// IntrNoMem; LDS reads can hoist above it).
//
// Slot-reuse safety: every wave is a producer; publishing version s+2
// requires its WG's barrier at s+1, which requires all 4 waves' polls to
// have seen ALL of version s+1, which requires every wave to have consumed
// its quarter of version s. Tags verify every word regardless.
// pbuf must be zeroed before launch (version 0 == zeros, tag 0).
// ---------------------------------------------------------------------------
__global__ __launch_bounds__(256, 1) void lstm_scan_kernel(
    const float* __restrict__ W_hh,
    const float* __restrict__ xp,              // [STEPS][GROWS]
    unsigned long long* __restrict__ pbuf,     // [32][2][HIDDEN]
    float* __restrict__ hs32,                  // [STEPS][HIDDEN]
    __bf16* __restrict__ hsbf,                 // [STEPS][HIDDEN]
    const int wbf)
{
    const int tid = threadIdx.x;
    const int rg  = tid >> 6;
    const int kc  = tid & 63;
    const int g   = blockIdx.x;            // 0..31
    const int w   = g * 4 + rg;            // global wave 0..127
    const int j0  = w * 4;

    __shared__ float hlds[2][HIDDEN];

    // lane -> (gate, elem) ownership after fold
    const int t_own  = ((kc & 1) << 1) | ((kc >> 1) & 1);
    const int jj_own = (((kc >> 2) & 1) << 1) | ((kc >> 3) & 1);
    const int row_own = t_own * HIDDEN + j0 + jj_own;

    // multicast constants: lane publishes element (kc&3) to copies c0, c0+16
    const int e_pub = kc & 3;
    const int src_lane = sel4i(0, 8, 4, 12, e_pub);  // canonical owner lane
    const int c0 = kc >> 2;                          // 0..15
    unsigned long long* const mc0 = pbuf + (size_t)c0 * 2 * HIDDEN + j0 + e_pub;
    unsigned long long* const mc1 = mc0 + (size_t)16 * 2 * HIDDEN;

    // ---- W_hh slice into registers: 16 rows x 8 k-chunk per lane ----
    float Whh[4][4][8];
#pragma unroll
    for (int t = 0; t < 4; ++t) {
#pragma unroll
        for (int jj = 0; jj < 4; ++jj) {
            const int row = t * HIDDEN + j0 + jj;
            const float4* ph = (const float4*)(W_hh + (size_t)row * HIDDEN + kc * 8);
            const float4 h0 = ph[0], h1 = ph[1];
            Whh[t][jj][0] = h0.x; Whh[t][jj][1] = h0.y; Whh[t][jj][2] = h0.z; Whh[t][jj][3] = h0.w;
            Whh[t][jj][4] = h1.x; Whh[t][jj][5] = h1.y; Whh[t][jj][6] = h1.z; Whh[t][jj][7] = h1.w;
        }
    }

    float c_state = 0.0f;
    float xpv = xp[row_own];               // xp for s = 0
    float xpv_next;
    const int qi = rg * 128 + kc * 2;      // my quarter words within my copy

    for (int s = 0; s < STEPS; ++s) {
        const int p = s & 1;
        const unsigned expect = (unsigned)s;

        // ---- poll my quarter of version s: load+wait fused in ONE asm ----
        const unsigned long long fa =
            (unsigned long long)(pbuf + ((size_t)g * 2 + p) * HIDDEN + qi);
        unsigned d0, d1;
        for (;;) {
            u32x4v v;
            asm volatile("global_load_dwordx4 %0, %1, off sc0 sc1\n\t"
                         "s_waitcnt vmcnt(0)"
                         : "=&v"(v) : "v"(fa) : "memory");
            if (__all((int)((v.y == expect) & (v.w == expect)))) {
                d0 = v.x; d1 = v.z; break;
            }
        }

        // ---- exchange within WG via LDS (full __syncthreads: see header) ----
        hlds[p][qi]     = __uint_as_float(d0);
        hlds[p][qi + 1] = __uint_as_float(d1);
        __syncthreads();

        float hreg[8];
        {
            const float4 a = *(const float4*)&hlds[p][kc * 8];
            const float4 b = *(const float4*)&hlds[p][kc * 8 + 4];
            hreg[0] = a.x; hreg[1] = a.y; hreg[2] = a.z; hreg[3] = a.w;
            hreg[4] = b.x; hreg[5] = b.y; hreg[6] = b.z; hreg[7] = b.w;
        }

        // ---- prefetch next step's xp (hidden under FMA phase) ----
        const int sn = (s + 1 < STEPS) ? (s + 1) : (STEPS - 1);
        xpv_next = xp[(size_t)sn * GROWS + row_own];

        // ---- h contribution: 16 rows x 8 k ----
        float acc[16];
#pragma unroll
        for (int t = 0; t < 4; ++t) {
#pragma unroll
            for (int jj = 0; jj < 4; ++jj) {
                float a = Whh[t][jj][0] * hreg[0];
#pragma unroll
                for (int kk = 1; kk < 8; ++kk)
                    a = fmaf(Whh[t][jj][kk], hreg[kk], a);
                acc[t * 4 + jj] = a;
            }
        }

        // ---- fold-reduce 16 x 64 lanes -> full sum per lane ----
#pragma unroll
        for (int i = 0; i < 8; ++i) {
            const float send = (kc & 1) ? acc[i] : acc[i + 8];
            const float keep = (kc & 1) ? acc[i + 8] : acc[i];
            acc[i] = keep + __shfl_xor(send, 1, 64);
        }
#pragma unroll
        for (int i = 0; i < 4; ++i) {
            const float send = (kc & 2) ? acc[i] : acc[i + 4];
            const float keep = (kc & 2) ? acc[i + 4] : acc[i];
            acc[i] = keep + __shfl_xor(send, 2, 64);
        }
#pragma unroll
        for (int i = 0; i < 2; ++i) {
            const float send = (kc & 4) ? acc[i] : acc[i + 2];
            const float keep = (kc & 4) ? acc[i + 2] : acc[i];
            acc[i] = keep + __shfl_xor(send, 4, 64);
        }
        {
            const float send = (kc & 8) ? acc[0] : acc[1];
            const float keep = (kc & 8) ? acc[1] : acc[0];
            acc[0] = keep + __shfl_xor(send, 8, 64);
        }
        float a = acc[0];
        a += __shfl_xor(a, 16, 64);
        a += __shfl_xor(a, 32, 64);
        a += xpv;   // full gate pre-activation for (t_own, jj_own)

        // ---- gather the 4 gates of MY element ----
        const float g00 = a;
        const float g01 = __shfl_xor(a, 1, 64);
        const float g10 = __shfl_xor(a, 2, 64);
        const float g11 = __shfl_xor(g01, 2, 64);
        float gi = sel4(g00, g10, g01, g11, t_own);
        float gf = sel4(g00, g10, g01, g11, t_own ^ 1);
        float gg = sel4(g00, g10, g01, g11, t_own ^ 2);
        float go = sel4(g00, g10, g01, g11, t_own ^ 3);

        gi = sigmoid_f(gi);
        gf = sigmoid_f(gf);
        gg = tanh_f(gg);
        go = sigmoid_f(go);
        c_state = gf * c_state + gi * gg;
        const float hnew = go * tanh_f(c_state);

        // ---- publish version s+1: multicast to all 32 copies ----
        const int q = (s + 1) & 1;
        const float hsrc = __shfl(hnew, src_lane, 64);   // value of element e_pub
        const unsigned long long pack =
            ((unsigned long long)(unsigned)(s + 1) << 32) |
            (unsigned long long)__float_as_uint(hsrc);
        __hip_atomic_store(mc0 + (size_t)q * HIDDEN, pack,
                           __ATOMIC_RELAXED, __HIP_MEMORY_SCOPE_AGENT);
        __hip_atomic_store(mc1 + (size_t)q * HIDDEN, pack,
                           __ATOMIC_RELAXED, __HIP_MEMORY_SCOPE_AGENT);

        // ---- trace store (owner lanes only) ----
        if ((kc & 0x33) == 0) {
            const int j = j0 + jj_own;
            if (wbf) hsbf[(size_t)s * HIDDEN + j] = (__bf16)hnew;
            else     hs32[(size_t)s * HIDDEN + j] = hnew;
        }

        xpv = xpv_next;
    }
}

// ---------------------------------------------------------------------------
// Kernel 1b: convert the xp-protected tail of W_out after the scan.
// ---------------------------------------------------------------------------
__global__ __launch_bounds__(256) void convert_tail_kernel(
    const float* __restrict__ W, unsigned short* __restrict__ Wb,
    int lo, int n)
{
    const int stride = gridDim.x * blockDim.x * 4;
    for (int i = lo + (blockIdx.x * blockDim.x + threadIdx.x) * 4; i < n; i += stride) {
        const float4 v = *(const float4*)(W + i);
        ushort4 o;
        o.x = f2bf_u16(v.x); o.y = f2bf_u16(v.y);
        o.z = f2bf_u16(v.z); o.w = f2bf_u16(v.w);
        *(ushort4*)(Wb + i) = o;
    }
}

// ---------------------------------------------------------------------------
// Kernel 2: logits = hs_bf16 @ Wb^T + b_out via MFMA (M=1024,N=32000,K=512).
// ---------------------------------------------------------------------------
__global__ __launch_bounds__(256) void logits_mfma_kernel(
    const __bf16* __restrict__ A,
    const __bf16* __restrict__ B,
    const float* __restrict__ b_out,
    float* __restrict__ out)
{
    __shared__ char AsR[16384];
    __shared__ char BsR[16384];
    const int tid  = threadIdx.x;
    const int lane = tid & 63;
    const int wave = tid >> 6;
    const int wm = (wave >> 1) * 64;
    const int wn = (wave & 1) * 64;
    const int n0 = blockIdx.x * 128;
    const int m0 = blockIdx.y * 128;

    f32x4 acc[4][4] = {};

    for (int k0 = 0; k0 < HIDDEN; k0 += 64) {
        if (k0) __syncthreads();
#pragma unroll
        for (int i = 0; i < 4; ++i) {
            const int o   = (tid + i * 256) << 4;
            const int row = o >> 7;
            const int cb  = o & 127;
            const int sc  = cb ^ ((row & 7) << 4);
            const bf16x8 av = *(const bf16x8*)(A + (size_t)(m0 + row) * HIDDEN + k0 + (cb >> 1));
            const bf16x8 bv = *(const bf16x8*)(B + (size_t)(n0 + row) * HIDDEN + k0 + (cb >> 1));
            *(bf16x8*)(AsR + row * 128 + sc) = av;
            *(bf16x8*)(BsR + row * 128 + sc) = bv;
        }
        __syncthreads();
#pragma unroll
        for (int ks = 0; ks < 2; ++ks) {
            const int kb = ks * 64 + ((lane >> 4) << 4);
            bf16x8 af[4], bfr[4];
#pragma unroll
            for (int mi = 0; mi < 4; ++mi) {
                const int r = wm + mi * 16 + (lane & 15);
                af[mi] = *(const bf16x8*)(AsR + r * 128 + (kb ^ ((r & 7) << 4)));
            }
#pragma unroll
            for (int ni = 0; ni < 4; ++ni) {
                const int r = wn + ni * 16 + (lane & 15);
                bfr[ni] = *(const bf16x8*)(BsR + r * 128 + (kb ^ ((r & 7) << 4)));
            }
#pragma unroll
            for (int mi = 0; mi < 4; ++mi)
#pragma unroll
                for (int ni = 0; ni < 4; ++ni)
                    acc[mi][ni] = __builtin_amdgcn_mfma_f32_16x16x32_bf16(
                        af[mi], bfr[ni], acc[mi][ni], 0, 0, 0);
        }
    }

#pragma unroll
    for (int ni = 0; ni < 4; ++ni) {
        const int col = n0 + wn + ni * 16 + (lane & 15);
        const float bo = b_out[col];
#pragma unroll
        for (int mi = 0; mi < 4; ++mi) {
            const int r0 = m0 + wm + mi * 16 + ((lane >> 4) << 2);
#pragma unroll
            for (int qq = 0; qq < 4; ++qq)
                out[(size_t)(r0 + qq) * VOCAB + col] = acc[mi][ni][qq] + bo;
        }
    }
}

// ---------------------------------------------------------------------------
// Kernel 2-fallback: fp32 vector GEMM.
// ---------------------------------------------------------------------------
__global__ __launch_bounds__(256) void logits_kernel(
    const float* __restrict__ hs,
    const float* __restrict__ W_out,
    const float* __restrict__ b_out,
    float* __restrict__ out)
{
    __shared__ float As[64][65];
    __shared__ float Bs[64][65];
    const int tid = threadIdx.x;
    const int tx = tid & 15, ty = tid >> 4;
    const int v0 = blockIdx.x * 64;
    const int s0 = blockIdx.y * 64;
    float accv[4][4] = {};

    for (int k0 = 0; k0 < HIDDEN; k0 += 64) {
#pragma unroll
        for (int i = 0; i < 4; ++i) {
            const int idx = tid + i * 256;
            const int r = idx >> 4, q = idx & 15;
            const float4 a = *(const float4*)(hs + (size_t)(s0 + r) * HIDDEN + k0 + q * 4);
            As[r][q * 4 + 0] = a.x; As[r][q * 4 + 1] = a.y;
            As[r][q * 4 + 2] = a.z; As[r][q * 4 + 3] = a.w;
            const float4 b = *(const float4*)(W_out + (size_t)(v0 + r) * HIDDEN + k0 + q * 4);
            Bs[r][q * 4 + 0] = b.x; Bs[r][q * 4 + 1] = b.y;
            Bs[r][q * 4 + 2] = b.z; Bs[r][q * 4 + 3] = b.w;
        }
        __syncthreads();
#pragma unroll 16
        for (int kk = 0; kk < 64; ++kk) {
            float av[4], bv[4];
#pragma unroll
            for (int i = 0; i < 4; ++i) av[i] = As[ty * 4 + i][kk];
#pragma unroll
            for (int j = 0; j < 4; ++j) bv[j] = Bs[tx * 4 + j][kk];
#pragma unroll
            for (int i = 0; i < 4; ++i)
#pragma unroll
                for (int j = 0; j < 4; ++j)
                    accv[i][j] = fmaf(av[i], bv[j], accv[i][j]);
        }
        __syncthreads();
    }
#pragma unroll
    for (int i = 0; i < 4; ++i) {
        const int s = s0 + ty * 4 + i;
#pragma unroll
        for (int j = 0; j < 4; ++j) {
            const int v = v0 + tx * 4 + j;
            out[(size_t)s * VOCAB + v] = accv[i][j] + b_out[v];
        }
    }
}

// ---------------------------------------------------------------------------
// Kernel 3: in-place row softmax, one WG per row of 32000.
// ---------------------------------------------------------------------------
__global__ __launch_bounds__(256) void softmax_kernel(float* __restrict__ out)
{
    const int row = blockIdx.x;
    float* p = out + (size_t)row * VOCAB;
    const int tid = threadIdx.x;
    __shared__ float redm[4];
    __shared__ float reds[4];

    float m = -3.402823466e38f;
    for (int idx = tid * 4; idx < VOCAB; idx += 1024) {
        const float4 v = *(const float4*)(p + idx);
        m = fmaxf(m, fmaxf(fmaxf(v.x, v.y), fmaxf(v.z, v.w)));
    }
#pragma unroll
    for (int d = 1; d < 64; d <<= 1) m = fmaxf(m, __shfl_xor(m, d, 64));
    if ((tid & 63) == 0) redm[tid >> 6] = m;
    __syncthreads();
    m = fmaxf(fmaxf(redm[0], redm[1]), fmaxf(redm[2], redm[3]));

    float sum = 0.f;
    for (int idx = tid * 4; idx < VOCAB; idx += 1024) {
        const float4 v = *(const float4*)(p + idx);
        sum += __expf(v.x - m) + __expf(v.y - m) + __expf(v.z - m) + __expf(v.w - m);
    }
#pragma unroll
    for (int d = 1; d < 64; d <<= 1) sum += __shfl_xor(sum, d, 64);
    if ((tid & 63) == 0) reds[tid >> 6] = sum;
    __syncthreads();
    sum = reds[0] + reds[1] + reds[2] + reds[3];
    const float inv = 1.0f / sum;

    for (int idx = tid * 4; idx < VOCAB; idx += 1024) {
        const float4 v = *(const float4*)(p + idx);
        float4 o;
        o.x = __expf(v.x - m) * inv;
        o.y = __expf(v.y - m) * inv;
        o.z = __expf(v.z - m) * inv;
        o.w = __expf(v.w - m) * inv;
        *(float4*)(p + idx) = o;
    }
}

// ---------------------------------------------------------------------------
// launch
// ---------------------------------------------------------------------------
extern "C" void kernel_launch(void* const* d_in, const int* in_sizes, int n_in,
                              void* d_out, int out_size, void* d_ws, size_t ws_size,
                              hipStream_t stream)
{
    const float* features = (const float*)d_in[0];
    const int*   captions = (const int*)d_in[1];
    const float* emb      = (const float*)d_in[2];
    const float* W_ih     = (const float*)d_in[3];
    const float* W_hh     = (const float*)d_in[4];
    const float* b_ih     = (const float*)d_in[5];
    const float* b_hh     = (const float*)d_in[6];
    const float* W_out    = (const float*)d_in[7];
    const float* b_out    = (const float*)d_in[8];
    float* out = (float*)d_out;

    char* ws = (char*)d_ws;
    unsigned long long* pbuf = (unsigned long long*)(ws + WS_PBUF);
    __bf16*             hsbf = (__bf16*)(ws + WS_HSBF);
    float*              hs32 = (float*)(ws + WS_HS32);
    __bf16*             Wb   = (__bf16*)(ws + WS_WB);
    const bool mfma_ok = ws_size >= WS_NEED;
    float* xpb = mfma_ok ? (float*)(ws + WS_WB + WS_XPOFF) : (float*)(ws + WS_WB);

    // zero mailboxes (version 0 == zeros, tag 0) — graph-replay deterministic
    hipMemsetAsync(d_ws, 0, 32 * 2 * HIDDEN * 8, stream);

    xproj_conv_kernel<<<dim3(32, 24), 256, 0, stream>>>(
        features, captions, emb, W_ih, b_ih, b_hh, xpb,
        W_out, (unsigned short*)Wb, mfma_ok ? 1 : 0);

    lstm_scan_kernel<<<32, 256, 0, stream>>>(
        W_hh, xpb, pbuf, hs32, hsbf, mfma_ok ? 1 : 0);

    if (mfma_ok) {
        convert_tail_kernel<<<512, 256, 0, stream>>>(
            W_out, (unsigned short*)Wb, WB_HEAD_ELEMS, VOCAB * HIDDEN);
        logits_mfma_kernel<<<dim3(VOCAB / 128, STEPS / 128), 256, 0, stream>>>(
            hsbf, Wb, b_out, out);
    } else {
        logits_kernel<<<dim3(VOCAB / 64, STEPS / 64), 256, 0, stream>>>(
            hs32, W_out, b_out, out);
    }
    softmax_kernel<<<STEPS, 256, 0, stream>>>(out);
}